// Round 7
// baseline (165.318 us; speedup 1.0000x reference)
//
#include <hip/hip_runtime.h>

// Problem constants (X, Y: (64, 128, 64) fp32)
#define AA   64
#define MM   128
#define DD   64
#define CSTR 132                 // inc row stride (words); 132%32=4 -> 2-way banks (free)
#define NXY  512                 // XY gram blocks (4096 pairs, 8/block: 1 b x 8 a)
#define NTRI 288                 // triangle blocks per symmetric gram (8 pairs/block)
#define NBLK (NXY + 2*NTRI)      // 1088
// ws layout: [0,4MB) frag regions {Xhi,Xlo,Yhi,Ylo} each 1MB =
//   path(64) x tile(8) x ks(2) x lane(64) x int4 ; [4MB,..) NBLK partials.
#define REG_I4 65536             // int4 per 1MB region
#define PART_OFF (4u << 20)

typedef float f32x4 __attribute__((ext_vector_type(4)));
typedef short bf8_t __attribute__((ext_vector_type(8)));

template <int CTRL, int RM>
__device__ __forceinline__ float dpp0(float x) {
    return __int_as_float(
        __builtin_amdgcn_update_dpp(0, __float_as_int(x), CTRL, RM, 0xF, false));
}

__device__ __forceinline__ unsigned bf16_rne(float v) {
    unsigned u = __float_as_uint(v);
    return (u + 0x7FFFu + ((u >> 16) & 1u)) >> 16;
}
__device__ __forceinline__ float bf16_tof(unsigned h) {
    return __uint_as_float(h << 16);
}

// Fence before overwriting an inc buffer: lgkmcnt(0) guarantees all prior
// ds_reads returned (R5-verified scheme). Placed so the waited-on loads were
// consumed by a chain already -> near-free.
__device__ __forceinline__ void lds_fence() {
    asm volatile("s_waitcnt lgkmcnt(0)" ::: "memory");
    __builtin_amdgcn_sched_barrier(0);
}

// ---------------------------------------------------------------------------
// prep: build hi/lo bf16 fragments of dX/dY once, in MFMA fragment order.
// (unchanged, harness-verified)
// ---------------------------------------------------------------------------
__global__ __launch_bounds__(256) void prep_frags(const float* __restrict__ X,
                                                  const float* __restrict__ Y,
                                                  int4* __restrict__ frag) {
    const int tid = threadIdx.x, lane = tid & 63, w = tid >> 6;
    const int W    = blockIdx.x * 4 + w;   // 0..1023
    const int inp  = W >> 9;               // 0: X, 1: Y
    const int p    = (W >> 3) & 63;
    const int tile = W & 7;
    const float* S = (inp ? Y : X) + p * (MM * DD);
    int i = tile * 16 + (lane & 15);
    if (i > 126) i = 126;
    const int d0 = (lane >> 4) << 3;

    int4* hi = frag + (inp * 2 + 0) * REG_I4;
    int4* lo = frag + (inp * 2 + 1) * REG_I4;
    const int base = p * 1024 + tile * 128 + lane;

    #pragma unroll
    for (int ks = 0; ks < 2; ++ks) {
        const float* r0 = S + i * DD + ks * 32 + d0;
        const float* r1 = r0 + DD;
        float4 a0 = *(const float4*)r0;
        float4 a1 = *(const float4*)(r0 + 4);
        float4 c0 = *(const float4*)r1;
        float4 c1 = *(const float4*)(r1 + 4);
        float v[8] = {c0.x - a0.x, c0.y - a0.y, c0.z - a0.z, c0.w - a0.w,
                      c1.x - a1.x, c1.y - a1.y, c1.z - a1.z, c1.w - a1.w};
        unsigned hs[8], ls[8];
        #pragma unroll
        for (int e = 0; e < 8; ++e) {
            hs[e] = bf16_rne(v[e]);
            ls[e] = bf16_rne(v[e] - bf16_tof(hs[e]));
        }
        int4 h, l;
        h.x = hs[0] | (hs[1] << 16); h.y = hs[2] | (hs[3] << 16);
        h.z = hs[4] | (hs[5] << 16); h.w = hs[6] | (hs[7] << 16);
        l.x = ls[0] | (ls[1] << 16); l.y = ls[2] | (ls[3] << 16);
        l.z = ls[4] | (ls[5] << 16); l.w = ls[6] | (ls[7] << 16);
        hi[base + ks * 64] = h;
        lo[base + ks * 64] = l;
    }
}

// ---------------------------------------------------------------------------
// Scan helpers. Per-row recurrence (R5-verified). v6: TWO independent pairs
// interleaved row-by-row -- two dep chains in one issue stream halve the
// exposed DPP/VALU dependency latency (the invariant wall of v2/v5).
// ---------------------------------------------------------------------------
template <int ROWS>
__device__ __forceinline__ void load_sv(const float* buf, int c2l, float2* sv) {
    #pragma unroll
    for (int r = 0; r < ROWS; ++r)
        sv[r] = *(const float2*)(buf + r * CSTR + c2l);
}

template <int ROWS>
__device__ __forceinline__ void chain2_sv(const float2* svP, const float2* svQ,
                                          int lane,
                                          float& S0, float& e00, float& e10,
                                          float& S1, float& e01, float& e11) {
    #pragma unroll
    for (int r = 0; r < ROWS; ++r) {
        float s0a = svP[r].x, s1a = (lane < 63) ? svP[r].y : 0.0f;
        float s0b = svQ[r].x, s1b = (lane < 63) ? svQ[r].y : 0.0f;
        float Spa = dpp0<0x138, 0xF>(S0);
        float Spb = dpp0<0x138, 0xF>(S1);
        float k0a = 1.0f + Spa, k1a = 1.0f + S0 - e10;
        float k0b = 1.0f + Spb, k1b = 1.0f + S1 - e11;
        float e0a = fmaf(k0a, s0a, e00), e1a = fmaf(k1a, s1a, e10);
        float e0b = fmaf(k0b, s0b, e01), e1b = fmaf(k1b, s1b, e11);
        float Sa = e0a + e1a;
        float Sb = e0b + e1b;
        Sa += dpp0<0x111, 0xF>(Sa);  Sb += dpp0<0x111, 0xF>(Sb);
        Sa += dpp0<0x112, 0xF>(Sa);  Sb += dpp0<0x112, 0xF>(Sb);
        Sa += dpp0<0x114, 0xF>(Sa);  Sb += dpp0<0x114, 0xF>(Sb);
        Sa += dpp0<0x118, 0xF>(Sa);  Sb += dpp0<0x118, 0xF>(Sb);
        Sa += dpp0<0x142, 0xA>(Sa);  Sb += dpp0<0x142, 0xA>(Sb);
        Sa += dpp0<0x143, 0xC>(Sa);  Sb += dpp0<0x143, 0xC>(Sb);
        S0 = Sa; e00 = e0a; e10 = e1a;
        S1 = Sb; e01 = e0b; e11 = e1b;
    }
}

// ---------------------------------------------------------------------------
// PDE kernel, 2 pairs per wave (8 per block, same b).
// gid < 512: XY (b = gid>>3, a = (gid&7)*8 + 2w + p), wgt -2/4096.
// Else triangle: b-groups of 8 share blocks-per-b = g+1; ragged a>b wgt 0.
// Per strip: {fence; store half for both pairs; load both} x2 clusters, each
// followed by the dual interleaved chain; MFMA for strip s+1 (B read once,
// both pairs) issues under the second chain. LDS 66.6 KB -> 2 blocks/CU.
// ---------------------------------------------------------------------------
__global__ __launch_bounds__(256, 2)
void sig_pde(const int4* __restrict__ frag, float* __restrict__ partials) {
    const int tid = threadIdx.x, lane = tid & 63, w = tid >> 6;
    const int gid = blockIdx.x;

    int b, a0, a1, ain, bin;
    float wgt0, wgt1;
    if (gid < NXY) {
        b = gid >> 3;
        int abase = (gid & 7) * 8;
        a0 = abase + 2 * w; a1 = a0 + 1;
        ain = 0; bin = 1;
        wgt0 = wgt1 = -2.0f / 4096.0f;
    } else {
        int t = gid - NXY;
        int inp = 0;
        if (t >= NTRI) { t -= NTRI; inp = 1; }
        int g = (int)((__builtin_sqrtf((float)(t + 1)) - 1.0f) * 0.5f);
        while (4 * (g + 1) * (g + 2) <= t) ++g;
        while (g > 0 && 4 * g * (g + 1) > t) --g;
        int r  = t - 4 * g * (g + 1);
        int bi = r / (g + 1);
        int c  = r - bi * (g + 1);
        b = 8 * g + bi;
        int abase = c * 8;
        a0 = abase + 2 * w; a1 = a0 + 1;
        ain = bin = inp;
        wgt0 = (a0 < b) ? (2.0f / 4096.0f) : ((a0 == b) ? (1.0f / 4096.0f) : 0.0f);
        wgt1 = (a1 < b) ? (2.0f / 4096.0f) : ((a1 == b) ? (1.0f / 4096.0f) : 0.0f);
    }

    __shared__ int4  Bh[1024], Bl[1024];     // 32 KB B fragments (hi/lo)
    __shared__ float incS[8][8 * CSTR];      // 33.8 KB: 2 bufs per wave
    __shared__ float red8[8];

    {   // stage this block's B fragment set
        const int4* Bhg = frag + (bin * 2 + 0) * REG_I4 + b * 1024;
        const int4* Blg = frag + (bin * 2 + 1) * REG_I4 + b * 1024;
        #pragma unroll
        for (int c = 0; c < 4; ++c) {
            int idx = c * 256 + tid;
            Bh[idx] = Bhg[idx];
            Bl[idx] = Blg[idx];
        }
    }
    __syncthreads();

    const int4* Ahg0 = frag + (ain * 2 + 0) * REG_I4 + a0 * 1024;
    const int4* Alg0 = frag + (ain * 2 + 1) * REG_I4 + a0 * 1024;
    const int4* Ahg1 = frag + (ain * 2 + 0) * REG_I4 + a1 * 1024;
    const int4* Alg1 = frag + (ain * 2 + 1) * REG_I4 + a1 * 1024;

    int4 A0h[2], A0l[2], A1h[2], A1l[2];     // current strip A frags (2 pairs)
    int4 N0h[2], N0l[2], N1h[2], N1l[2];     // prefetched next strip
    f32x4 acc[2][8];                          // 64 AGPR: both pairs' strips
    float S0 = 0.f, e00 = 0.f, e10 = 0.f;    // pair0 scan state
    float S1 = 0.f, e01 = 0.f, e11 = 0.f;    // pair1 scan state

    float* buf0 = &incS[2 * w + 0][0];
    float* buf1 = &incS[2 * w + 1][0];
    const int c2l = lane << 1;
    const int r0w = (lane >> 4) << 2, c0w = lane & 15;

// 96 MFMA for both pairs; each B fragment read ONCE feeds both.
#define MFMA_PASS() do {                                                        \
    _Pragma("unroll")                                                           \
    for (int p_ = 0; p_ < 2; ++p_)                                              \
        _Pragma("unroll")                                                       \
        for (int t_ = 0; t_ < 8; ++t_) acc[p_][t_] = (f32x4){0.f,0.f,0.f,0.f};  \
    _Pragma("unroll")                                                           \
    for (int s_ = 0; s_ < 2; ++s_) {                                            \
        bf8_t ah0 = __builtin_bit_cast(bf8_t, A0h[s_]);                         \
        bf8_t al0 = __builtin_bit_cast(bf8_t, A0l[s_]);                         \
        bf8_t ah1 = __builtin_bit_cast(bf8_t, A1h[s_]);                         \
        bf8_t al1 = __builtin_bit_cast(bf8_t, A1l[s_]);                         \
        _Pragma("unroll")                                                       \
        for (int t_ = 0; t_ < 8; ++t_) {                                        \
            int fb = (t_ * 2 + s_) * 64 + lane;                                 \
            bf8_t bh = *(const bf8_t*)&Bh[fb];                                  \
            bf8_t bl = *(const bf8_t*)&Bl[fb];                                  \
            acc[0][t_] = __builtin_amdgcn_mfma_f32_16x16x32_bf16(ah0, bh, acc[0][t_], 0, 0, 0); \
            acc[1][t_] = __builtin_amdgcn_mfma_f32_16x16x32_bf16(ah1, bh, acc[1][t_], 0, 0, 0); \
            acc[0][t_] = __builtin_amdgcn_mfma_f32_16x16x32_bf16(ah0, bl, acc[0][t_], 0, 0, 0); \
            acc[1][t_] = __builtin_amdgcn_mfma_f32_16x16x32_bf16(ah1, bl, acc[1][t_], 0, 0, 0); \
            acc[0][t_] = __builtin_amdgcn_mfma_f32_16x16x32_bf16(al0, bh, acc[0][t_], 0, 0, 0); \
            acc[1][t_] = __builtin_amdgcn_mfma_f32_16x16x32_bf16(al1, bh, acc[1][t_], 0, 0, 0); \
        }                                                                       \
    }                                                                           \
} while (0)

// Half-strip store of pair p's acc: half 0 from lanes r0w<8 (strip rows 0-7),
// half 1 from lanes r0w>=8 (rows 8-15); both land on buffer rows 0..7.
// Preceded (transitively) by lds_fence per R5-verified discipline.
#define STORE_H(p, half, buf) do {                             \
    if ((r0w & 8) == ((half) << 3)) {                          \
        float* pb = (buf) + (r0w & 7) * CSTR + c0w;            \
        _Pragma("unroll")                                      \
        for (int t_ = 0; t_ < 8; ++t_) {                       \
            float* q = pb + (t_ << 4);                         \
            q[0]        = acc[p][t_][0];                       \
            q[CSTR]     = acc[p][t_][1];                       \
            q[2 * CSTR] = acc[p][t_][2];                       \
            q[3 * CSTR] = acc[p][t_][3];                       \
        }                                                      \
    }                                                          \
} while (0)

#define LOAD_A_N(poff) do {                                    \
    int off = (poff) + lane;                                   \
    N0h[0] = Ahg0[off]; N0h[1] = Ahg0[off + 64];               \
    N0l[0] = Alg0[off]; N0l[1] = Alg0[off + 64];               \
    N1h[0] = Ahg1[off]; N1h[1] = Ahg1[off + 64];               \
    N1l[0] = Alg1[off]; N1l[1] = Alg1[off + 64];               \
} while (0)

    // prologue: strip 0 fragments + MFMAs
    A0h[0] = Ahg0[lane]; A0h[1] = Ahg0[64 + lane];
    A0l[0] = Alg0[lane]; A0l[1] = Alg0[64 + lane];
    A1h[0] = Ahg1[lane]; A1h[1] = Ahg1[64 + lane];
    A1l[0] = Alg1[lane]; A1l[1] = Alg1[64 + lane];
    MFMA_PASS();                             // acc = inc strip 0, both pairs

    for (int s = 0; s < 8; ++s) {
        if (s < 7) LOAD_A_N((s + 1) * 128);  // global prefetch, consumed at MFMA

        // ---- cluster 1: half 0 of both pairs ----------------------------
        float2 sv00[8], sv10[8];
        lds_fence();                          // prev loads consumed -> ~free
        STORE_H(0, 0, buf0); load_sv<8>(buf0, c2l, sv00);
        STORE_H(1, 0, buf1); load_sv<8>(buf1, c2l, sv10);
        chain2_sv<8>(sv00, sv10, lane, S0, e00, e10, S1, e01, e11);

        // ---- cluster 2: half 1 of both pairs ----------------------------
        lds_fence();                          // sv00/sv10 consumed -> ~free
        if (s < 7) {
            float2 sv01[8], sv11[8];
            STORE_H(0, 1, buf0); load_sv<8>(buf0, c2l, sv01);
            STORE_H(1, 1, buf1); load_sv<8>(buf1, c2l, sv11);
            A0h[0] = N0h[0]; A0h[1] = N0h[1]; A0l[0] = N0l[0]; A0l[1] = N0l[1];
            A1h[0] = N1h[0]; A1h[1] = N1h[1]; A1l[0] = N1l[0]; A1l[1] = N1l[1];
            MFMA_PASS();                      // next strip; executes under chain
            chain2_sv<8>(sv01, sv11, lane, S0, e00, e10, S1, e01, e11);
        } else {
            float2 sv01[7], sv11[7];          // last strip: rows 120..126
            STORE_H(0, 1, buf0); load_sv<7>(buf0, c2l, sv01);
            STORE_H(1, 1, buf1); load_sv<7>(buf1, c2l, sv11);
            chain2_sv<7>(sv01, sv11, lane, S0, e00, e10, S1, e01, e11);
        }
    }

    if (lane == 63) {
        red8[2 * w + 0] = wgt0 * (1.0f + S0 - e10);  // K[127][127] pair0
        red8[2 * w + 1] = wgt1 * (1.0f + S1 - e11);  // K[127][127] pair1
    }
    __syncthreads();
    if (tid == 0) {
        float r = 0.f;
        #pragma unroll
        for (int i = 0; i < 8; ++i) r += red8[i];
        partials[gid] = r;
    }

#undef MFMA_PASS
#undef STORE_H
#undef LOAD_A_N
}

// ---------------------------------------------------------------------------
// final: out[0] = sum(partials) + mean((X0-Y0)^2).
// ---------------------------------------------------------------------------
__global__ void final_sum(const float* __restrict__ X, const float* __restrict__ Y,
                          const float* __restrict__ partials, float* __restrict__ out) {
    __shared__ float red[4];
    int tid = threadIdx.x;                   // 256 threads
    float acc = 0.f;
    for (int e = tid; e < NBLK; e += 256) acc += partials[e];
    for (int e = tid; e < AA * DD; e += 256) {
        int aa = e >> 6, d = e & 63;
        float df = X[aa * (MM * DD) + d] - Y[aa * (MM * DD) + d];
        acc = fmaf(df * df, 1.0f / 4096.0f, acc);
    }
    #pragma unroll
    for (int off = 32; off > 0; off >>= 1) acc += __shfl_down(acc, off);
    if ((tid & 63) == 0) red[tid >> 6] = acc;
    __syncthreads();
    if (tid == 0) out[0] = red[0] + red[1] + red[2] + red[3];
}

extern "C" void kernel_launch(void* const* d_in, const int* in_sizes, int n_in,
                              void* d_out, int out_size, void* d_ws, size_t ws_size,
                              hipStream_t stream) {
    const float* X = (const float*)d_in[0];
    const float* Y = (const float*)d_in[1];
    float* out = (float*)d_out;
    int4*  frag = (int4*)d_ws;
    float* partials = (float*)((char*)d_ws + PART_OFF);

    hipLaunchKernelGGL(prep_frags, dim3(256), dim3(256), 0, stream, X, Y, frag);
    hipLaunchKernelGGL(sig_pde, dim3(NBLK), dim3(256), 0, stream, frag, partials);
    hipLaunchKernelGGL(final_sum, dim3(1), dim3(256), 0, stream, X, Y, partials, out);
}